// Round 1
// baseline (830.820 us; speedup 1.0000x reference)
//
#include <hip/hip_runtime.h>

#define BB 8
#define DD 512
#define NPIX 1600
#define KK 64
#define OUTN 4096
#define DKN 32768   // D*K

// ---------------------------------------------------------------------------
// K1: scores = conv_w @ feat  (per batch, 64x64 n-tiles), fused softmax over K,
//     writes assignT[b][n][k] (transposed for K2) and atomically accumulates
//     asum[b][k] = sum_n assign[b,k,n].
// ---------------------------------------------------------------------------
__global__ __launch_bounds__(256) void k1_scores(
    const float* __restrict__ x, const float* __restrict__ convw,
    float* __restrict__ assignT, float* __restrict__ asum) {
  __shared__ float cws[64 * 68];  // [k][dd], reused as scoreT[n][k]
  __shared__ float xs[64 * 68];   // [dd][nn]
  int t = threadIdx.x;
  int b = blockIdx.y;
  int n0 = blockIdx.x * 64;
  int tn = t & 15, tk = t >> 4;
  int r = t >> 2, c = (t & 3) * 16;
  float acc[4][4] = {};

  for (int d0 = 0; d0 < DD; d0 += 64) {
    const float* cw = convw + (long)r * DD + d0 + c;
    const float* xp = x + ((long)(b * DD + d0 + r)) * NPIX + n0 + c;
#pragma unroll
    for (int q = 0; q < 4; q++) {
      *(float4*)(&cws[r * 68 + c + q * 4]) = *(const float4*)(cw + q * 4);
      *(float4*)(&xs[r * 68 + c + q * 4]) = *(const float4*)(xp + q * 4);
    }
    __syncthreads();
#pragma unroll 4
    for (int dd = 0; dd < 64; ++dd) {
      float a0 = cws[(tk * 4 + 0) * 68 + dd];
      float a1 = cws[(tk * 4 + 1) * 68 + dd];
      float a2 = cws[(tk * 4 + 2) * 68 + dd];
      float a3 = cws[(tk * 4 + 3) * 68 + dd];
      float4 bv = *(const float4*)(&xs[dd * 68 + tn * 4]);
      acc[0][0] += a0 * bv.x; acc[0][1] += a0 * bv.y; acc[0][2] += a0 * bv.z; acc[0][3] += a0 * bv.w;
      acc[1][0] += a1 * bv.x; acc[1][1] += a1 * bv.y; acc[1][2] += a1 * bv.z; acc[1][3] += a1 * bv.w;
      acc[2][0] += a2 * bv.x; acc[2][1] += a2 * bv.y; acc[2][2] += a2 * bv.z; acc[2][3] += a2 * bv.w;
      acc[3][0] += a3 * bv.x; acc[3][1] += a3 * bv.y; acc[3][2] += a3 * bv.z; acc[3][3] += a3 * bv.w;
    }
    __syncthreads();
  }

  // scores -> scoreT[n][k] in LDS (reuse cws)
#pragma unroll
  for (int i = 0; i < 4; i++)
#pragma unroll
    for (int j = 0; j < 4; j++)
      cws[(tn * 4 + j) * 68 + tk * 4 + i] = acc[i][j];
  __syncthreads();

  if (t < 64) {
    int n = t;
    float vv[64];
    float m = -1e30f;
#pragma unroll
    for (int k2 = 0; k2 < 64; k2++) {
      float s = cws[n * 68 + k2];
      vv[k2] = s;
      m = fmaxf(m, s);
    }
    float ssum = 0.f;
#pragma unroll
    for (int k2 = 0; k2 < 64; k2++) {
      float e = expf(vv[k2] - m);
      vv[k2] = e;
      ssum += e;
    }
    float inv = 1.0f / ssum;
    float* ap = assignT + ((long)b * NPIX + n0 + n) * KK;
#pragma unroll
    for (int k2 = 0; k2 < 64; k2 += 4) {
      float4 o;
      o.x = vv[k2 + 0] * inv; o.y = vv[k2 + 1] * inv;
      o.z = vv[k2 + 2] * inv; o.w = vv[k2 + 3] * inv;
      *(float4*)(ap + k2) = o;
      cws[n * 68 + k2 + 0] = o.x; cws[n * 68 + k2 + 1] = o.y;
      cws[n * 68 + k2 + 2] = o.z; cws[n * 68 + k2 + 3] = o.w;
    }
  }
  __syncthreads();
  if (t < 64) {
    int k2 = t;
    float s = 0.f;
#pragma unroll 8
    for (int nn = 0; nn < 64; nn++) s += cws[nn * 68 + k2];
    atomicAdd(&asum[b * KK + k2], s);
  }
}

// ---------------------------------------------------------------------------
// K2: vlad_part[ns][b][d][k] = sum_{n in chunk} x[b,d,n] * assignT[b][n][k]
// grid (8 d-tiles, 5 n-splits, 8 b), 64x64 output tile per block
// ---------------------------------------------------------------------------
__global__ __launch_bounds__(256) void k2_vlad(
    const float* __restrict__ x, const float* __restrict__ assignT,
    float* __restrict__ vlad_part) {
  __shared__ float xs[64 * 68];   // [dd][nn]
  __shared__ float as_[64 * 68];  // [nn][k]
  int t = threadIdx.x;
  int dt = blockIdx.x, ns = blockIdx.y, b = blockIdx.z;
  int d0 = dt * 64;
  int tk = t & 15, td = t >> 4;
  int r = t >> 2, c = (t & 3) * 16;
  float acc[4][4] = {};

  for (int nc = 0; nc < 320; nc += 64) {
    int n0 = ns * 320 + nc;
    const float* xp = x + ((long)(b * DD + d0 + r)) * NPIX + n0 + c;
    const float* ap = assignT + ((long)b * NPIX + n0 + r) * KK + c;
#pragma unroll
    for (int q = 0; q < 4; q++) {
      *(float4*)(&xs[r * 68 + c + q * 4]) = *(const float4*)(xp + q * 4);
      *(float4*)(&as_[r * 68 + c + q * 4]) = *(const float4*)(ap + q * 4);
    }
    __syncthreads();
#pragma unroll 4
    for (int nn = 0; nn < 64; ++nn) {
      float a0 = xs[(td * 4 + 0) * 68 + nn];
      float a1 = xs[(td * 4 + 1) * 68 + nn];
      float a2 = xs[(td * 4 + 2) * 68 + nn];
      float a3 = xs[(td * 4 + 3) * 68 + nn];
      float4 bv = *(const float4*)(&as_[nn * 68 + tk * 4]);
      acc[0][0] += a0 * bv.x; acc[0][1] += a0 * bv.y; acc[0][2] += a0 * bv.z; acc[0][3] += a0 * bv.w;
      acc[1][0] += a1 * bv.x; acc[1][1] += a1 * bv.y; acc[1][2] += a1 * bv.z; acc[1][3] += a1 * bv.w;
      acc[2][0] += a2 * bv.x; acc[2][1] += a2 * bv.y; acc[2][2] += a2 * bv.z; acc[2][3] += a2 * bv.w;
      acc[3][0] += a3 * bv.x; acc[3][1] += a3 * bv.y; acc[3][2] += a3 * bv.z; acc[3][3] += a3 * bv.w;
    }
    __syncthreads();
  }
  float* vp = vlad_part + (((long)ns * BB + b) * DD + d0) * KK;
#pragma unroll
  for (int i = 0; i < 4; i++) {
    float4 o = {acc[i][0], acc[i][1], acc[i][2], acc[i][3]};
    *(float4*)(vp + (td * 4 + i) * KK + tk * 4) = o;
  }
}

// ---------------------------------------------------------------------------
// K3: reduce 5 partials, subtract asum*centers, intra-normalize over D per
// (b,k), write desc[b][d*K+k], accumulate global sumsq per b.
// ---------------------------------------------------------------------------
__global__ __launch_bounds__(256) void k3_norm(
    const float* __restrict__ vlad_part, const float* __restrict__ asum,
    const float* __restrict__ centers, float* __restrict__ desc,
    float* __restrict__ gsq) {
  __shared__ float sred[4];
  int k = blockIdx.x, b = blockIdx.y;
  int t = threadIdx.x;
  float a = asum[b * KK + k];
  float v[2];
#pragma unroll
  for (int h = 0; h < 2; h++) {
    int d = t + h * 256;
    float s = 0.f;
#pragma unroll
    for (int p = 0; p < 5; p++)
      s += vlad_part[(((long)p * BB + b) * DD + d) * KK + k];
    s -= a * centers[(long)d * KK + k];
    v[h] = s;
  }
  float ss = v[0] * v[0] + v[1] * v[1];
  for (int off = 32; off > 0; off >>= 1) ss += __shfl_down(ss, off, 64);
  if ((t & 63) == 0) sred[t >> 6] = ss;
  __syncthreads();
  float tot = sred[0] + sred[1] + sred[2] + sred[3];
  float sc = 1.0f / fmaxf(sqrtf(tot), 1e-12f);
#pragma unroll
  for (int h = 0; h < 2; h++) {
    int d = t + h * 256;
    desc[(long)b * DKN + (long)d * KK + k] = v[h] * sc;
  }
  if (t == 0) atomicAdd(&gsq[b], tot * sc * sc);
}

// ---------------------------------------------------------------------------
// K4: whiten GEMM (memory-bound, streams W once).
// Block = 8 output rows x 8 batches; thread float4-strided over j.
// ---------------------------------------------------------------------------
__global__ __launch_bounds__(256) void k4_whiten(
    const float* __restrict__ desc, const float* __restrict__ W,
    float* __restrict__ ydot) {
  int t = threadIdx.x;
  long o0 = (long)blockIdx.x * 8;
  float acc[8][8];  // [oo][bb]
#pragma unroll
  for (int oo = 0; oo < 8; oo++)
#pragma unroll
    for (int bb = 0; bb < 8; bb++) acc[oo][bb] = 0.f;

  const float* wbase = W + o0 * DKN;
  for (int jt = 0; jt < DKN; jt += 1024) {
    int j = jt + t * 4;
    float4 d4[8];
#pragma unroll
    for (int bb = 0; bb < 8; bb++)
      d4[bb] = *(const float4*)(desc + (long)bb * DKN + j);
#pragma unroll
    for (int oo = 0; oo < 8; oo++) {
      float4 w4 = *(const float4*)(wbase + (long)oo * DKN + j);
#pragma unroll
      for (int bb = 0; bb < 8; bb++) {
        acc[oo][bb] += w4.x * d4[bb].x + w4.y * d4[bb].y +
                       w4.z * d4[bb].z + w4.w * d4[bb].w;
      }
    }
  }
  int lane = t & 63;
#pragma unroll
  for (int oo = 0; oo < 8; oo++)
#pragma unroll
    for (int bb = 0; bb < 8; bb++) {
      float v = acc[oo][bb];
      for (int off = 32; off > 0; off >>= 1) v += __shfl_down(v, off, 64);
      if (lane == 0) atomicAdd(&ydot[(long)bb * OUTN + o0 + oo], v);
    }
}

// ---------------------------------------------------------------------------
// K5: y = dot/gnorm + bias; final L2 normalize per row; write out.
// ---------------------------------------------------------------------------
__global__ __launch_bounds__(256) void k5_final(
    const float* __restrict__ ydot, const float* __restrict__ gsq,
    const float* __restrict__ bias, float* __restrict__ out) {
  __shared__ float sred[4];
  int b = blockIdx.x, t = threadIdx.x;
  float g = fmaxf(sqrtf(gsq[b]), 1e-12f);
  float inv_g = 1.0f / g;
  float v[16];
  float ss = 0.f;
#pragma unroll
  for (int i = 0; i < 16; i++) {
    int o = t + i * 256;
    float val = ydot[(long)b * OUTN + o] * inv_g + bias[o];
    v[i] = val;
    ss += val * val;
  }
  for (int off = 32; off > 0; off >>= 1) ss += __shfl_down(ss, off, 64);
  if ((t & 63) == 0) sred[t >> 6] = ss;
  __syncthreads();
  float tot = sred[0] + sred[1] + sred[2] + sred[3];
  float sc = 1.0f / fmaxf(sqrtf(tot), 1e-12f);
#pragma unroll
  for (int i = 0; i < 16; i++) {
    int o = t + i * 256;
    out[(long)b * OUTN + o] = v[i] * sc;
  }
}

extern "C" void kernel_launch(void* const* d_in, const int* in_sizes, int n_in,
                              void* d_out, int out_size, void* d_ws,
                              size_t ws_size, hipStream_t stream) {
  const float* x = (const float*)d_in[0];        // [8,512,40,40]
  const float* convw = (const float*)d_in[1];    // [64,512]
  const float* centers = (const float*)d_in[2];  // [512,64]
  const float* ww = (const float*)d_in[3];       // [4096,32768]
  const float* wb = (const float*)d_in[4];       // [4096]
  float* out = (float*)d_out;                    // [8,4096] f32

  // ws layout (floats):
  float* base = (float*)d_ws;
  float* ydot = base;                    // 8*4096      = 32768
  float* asum = base + 32768;            // 8*64        = 512
  float* gsq = base + 33280;             // 8
  float* assignT = base + 33288;         // 8*1600*64   = 819200
  float* desc = assignT;                 // reuse (assignT dead after k2)
  float* vlad_part = base + 33288 + 819200;  // 5*8*512*64 = 1310720

  // zero the atomic accumulators (ydot, asum, gsq)
  hipMemsetAsync(base, 0, 33288 * sizeof(float), stream);

  hipLaunchKernelGGL(k1_scores, dim3(25, 8), dim3(256), 0, stream, x, convw,
                     assignT, asum);
  hipLaunchKernelGGL(k2_vlad, dim3(8, 5, 8), dim3(256), 0, stream, x, assignT,
                     vlad_part);
  hipLaunchKernelGGL(k3_norm, dim3(64, 8), dim3(256), 0, stream, vlad_part,
                     asum, centers, desc, gsq);
  hipLaunchKernelGGL(k4_whiten, dim3(512), dim3(256), 0, stream, desc, ww,
                     ydot);
  hipLaunchKernelGGL(k5_final, dim3(8), dim3(256), 0, stream, ydot, gsq, wb,
                     out);
}

// Round 2
// 801.347 us; speedup vs baseline: 1.0368x; 1.0368x over previous
//
#include <hip/hip_runtime.h>

#define BB 8
#define DD 512
#define NPIX 1600
#define KK 64
#define OUTN 4096
#define DKN 32768   // D*K
#define NSPLIT 25   // one 64-wide n-tile per k2 block

// ---------------------------------------------------------------------------
// K1: scores = conv_w @ feat  (per batch, 64x64 n-tiles), fused softmax over K,
//     writes assignT[b][n][k] (transposed for K2) and atomically accumulates
//     asum[b][k] = sum_n assign[b,k,n].
// ---------------------------------------------------------------------------
__global__ __launch_bounds__(256) void k1_scores(
    const float* __restrict__ x, const float* __restrict__ convw,
    float* __restrict__ assignT, float* __restrict__ asum) {
  __shared__ float cws[64 * 68];  // [k][dd], reused as scoreT[n][k]
  __shared__ float xs[64 * 68];   // [dd][nn]
  int t = threadIdx.x;
  int b = blockIdx.y;
  int n0 = blockIdx.x * 64;
  int tn = t & 15, tk = t >> 4;
  int r = t >> 2, c = (t & 3) * 16;
  float acc[4][4] = {};

  for (int d0 = 0; d0 < DD; d0 += 64) {
    const float* cw = convw + (long)r * DD + d0 + c;
    const float* xp = x + ((long)(b * DD + d0 + r)) * NPIX + n0 + c;
#pragma unroll
    for (int q = 0; q < 4; q++) {
      *(float4*)(&cws[r * 68 + c + q * 4]) = *(const float4*)(cw + q * 4);
      *(float4*)(&xs[r * 68 + c + q * 4]) = *(const float4*)(xp + q * 4);
    }
    __syncthreads();
#pragma unroll 4
    for (int dd = 0; dd < 64; ++dd) {
      float a0 = cws[(tk * 4 + 0) * 68 + dd];
      float a1 = cws[(tk * 4 + 1) * 68 + dd];
      float a2 = cws[(tk * 4 + 2) * 68 + dd];
      float a3 = cws[(tk * 4 + 3) * 68 + dd];
      float4 bv = *(const float4*)(&xs[dd * 68 + tn * 4]);
      acc[0][0] += a0 * bv.x; acc[0][1] += a0 * bv.y; acc[0][2] += a0 * bv.z; acc[0][3] += a0 * bv.w;
      acc[1][0] += a1 * bv.x; acc[1][1] += a1 * bv.y; acc[1][2] += a1 * bv.z; acc[1][3] += a1 * bv.w;
      acc[2][0] += a2 * bv.x; acc[2][1] += a2 * bv.y; acc[2][2] += a2 * bv.z; acc[2][3] += a2 * bv.w;
      acc[3][0] += a3 * bv.x; acc[3][1] += a3 * bv.y; acc[3][2] += a3 * bv.z; acc[3][3] += a3 * bv.w;
    }
    __syncthreads();
  }

  // scores -> scoreT[n][k] in LDS (reuse cws)
#pragma unroll
  for (int i = 0; i < 4; i++)
#pragma unroll
    for (int j = 0; j < 4; j++)
      cws[(tn * 4 + j) * 68 + tk * 4 + i] = acc[i][j];
  __syncthreads();

  // softmax over k: 4 lanes cooperate per n (lanes 4n..4n+3, shfl_xor 1,2)
  {
    int n = t >> 2;           // 0..63
    int kq = (t & 3) * 16;    // 0,16,32,48
    float v[16];
    float m = -1e30f;
#pragma unroll
    for (int q = 0; q < 4; q++) {
      float4 s4 = *(const float4*)(&cws[n * 68 + kq + q * 4]);
      v[q * 4 + 0] = s4.x; v[q * 4 + 1] = s4.y;
      v[q * 4 + 2] = s4.z; v[q * 4 + 3] = s4.w;
      m = fmaxf(m, fmaxf(fmaxf(s4.x, s4.y), fmaxf(s4.z, s4.w)));
    }
    m = fmaxf(m, __shfl_xor(m, 1, 64));
    m = fmaxf(m, __shfl_xor(m, 2, 64));
    float ssum = 0.f;
#pragma unroll
    for (int i = 0; i < 16; i++) {
      v[i] = expf(v[i] - m);
      ssum += v[i];
    }
    ssum += __shfl_xor(ssum, 1, 64);
    ssum += __shfl_xor(ssum, 2, 64);
    float inv = 1.0f / ssum;
    float* ap = assignT + ((long)b * NPIX + n0 + n) * KK + kq;
#pragma unroll
    for (int q = 0; q < 4; q++) {
      float4 o;
      o.x = v[q * 4 + 0] * inv; o.y = v[q * 4 + 1] * inv;
      o.z = v[q * 4 + 2] * inv; o.w = v[q * 4 + 3] * inv;
      *(float4*)(ap + q * 4) = o;
      *(float4*)(&cws[n * 68 + kq + q * 4]) = o;
    }
  }
  __syncthreads();
  // asum partials: 256 threads, 4 partial atomics per (b,k)
  {
    int k2i = t & 63, ng = t >> 6;
    float s = 0.f;
#pragma unroll
    for (int nn = ng * 16; nn < ng * 16 + 16; nn++) s += cws[nn * 68 + k2i];
    atomicAdd(&asum[b * KK + k2i], s);
  }
}

// ---------------------------------------------------------------------------
// K2: vpT[ns][b][k][d] = sum_{n in tile ns} x[b,d,n] * assignT[b][n][k]
// grid (8 d-tiles, 25 n-tiles, 8 b); transposed [k][d] output so K3 reads
// are unit-stride.
// ---------------------------------------------------------------------------
__global__ __launch_bounds__(256) void k2_vlad(
    const float* __restrict__ x, const float* __restrict__ assignT,
    float* __restrict__ vpT) {
  __shared__ float xs[64 * 68];   // [dd][nn]
  __shared__ float as_[64 * 68];  // [nn][k]
  int t = threadIdx.x;
  int dt = blockIdx.x, ns = blockIdx.y, b = blockIdx.z;
  int d0 = dt * 64, n0 = ns * 64;
  int tk = t & 15, td = t >> 4;
  int r = t >> 2, c = (t & 3) * 16;
  float acc[4][4] = {};

  const float* xp = x + ((long)(b * DD + d0 + r)) * NPIX + n0 + c;
  const float* ap = assignT + ((long)b * NPIX + n0 + r) * KK + c;
#pragma unroll
  for (int q = 0; q < 4; q++) {
    *(float4*)(&xs[r * 68 + c + q * 4]) = *(const float4*)(xp + q * 4);
    *(float4*)(&as_[r * 68 + c + q * 4]) = *(const float4*)(ap + q * 4);
  }
  __syncthreads();
#pragma unroll 4
  for (int nn = 0; nn < 64; ++nn) {
    float a0 = xs[(td * 4 + 0) * 68 + nn];
    float a1 = xs[(td * 4 + 1) * 68 + nn];
    float a2 = xs[(td * 4 + 2) * 68 + nn];
    float a3 = xs[(td * 4 + 3) * 68 + nn];
    float4 bv = *(const float4*)(&as_[nn * 68 + tk * 4]);
    acc[0][0] += a0 * bv.x; acc[0][1] += a0 * bv.y; acc[0][2] += a0 * bv.z; acc[0][3] += a0 * bv.w;
    acc[1][0] += a1 * bv.x; acc[1][1] += a1 * bv.y; acc[1][2] += a1 * bv.z; acc[1][3] += a1 * bv.w;
    acc[2][0] += a2 * bv.x; acc[2][1] += a2 * bv.y; acc[2][2] += a2 * bv.z; acc[2][3] += a2 * bv.w;
    acc[3][0] += a3 * bv.x; acc[3][1] += a3 * bv.y; acc[3][2] += a3 * bv.z; acc[3][3] += a3 * bv.w;
  }
  // write transposed partial: vpT[((ns*8+b)*64+k)*512 + d], float4 over d
  float* vp = vpT + (((long)ns * BB + b) * KK) * DD;
#pragma unroll
  for (int j = 0; j < 4; j++) {
    int k = tk * 4 + j;
    float4 o = {acc[0][j], acc[1][j], acc[2][j], acc[3][j]};
    *(float4*)(vp + (long)k * DD + d0 + td * 4) = o;
  }
}

// ---------------------------------------------------------------------------
// K3: reduce 25 partials (unit-stride reads), subtract asum*centers,
// intra-normalize over D per (b,k), write desc[b][d*K+k], accumulate
// global sumsq per b (== K after normalization, but computed honestly).
// ---------------------------------------------------------------------------
__global__ __launch_bounds__(256) void k3_norm(
    const float* __restrict__ vpT, const float* __restrict__ asum,
    const float* __restrict__ centers, float* __restrict__ desc,
    float* __restrict__ gsq) {
  __shared__ float sred[4];
  int k = blockIdx.x, b = blockIdx.y;
  int t = threadIdx.x;
  float a = asum[b * KK + k];
  float v[2];
#pragma unroll
  for (int h = 0; h < 2; h++) {
    int d = t + h * 256;
    float s = 0.f;
#pragma unroll 5
    for (int p = 0; p < NSPLIT; p++)
      s += vpT[(((long)p * BB + b) * KK + k) * DD + d];
    s -= a * centers[(long)d * KK + k];
    v[h] = s;
  }
  float ss = v[0] * v[0] + v[1] * v[1];
  for (int off = 32; off > 0; off >>= 1) ss += __shfl_down(ss, off, 64);
  if ((t & 63) == 0) sred[t >> 6] = ss;
  __syncthreads();
  float tot = sred[0] + sred[1] + sred[2] + sred[3];
  float sc = 1.0f / fmaxf(sqrtf(tot), 1e-12f);
#pragma unroll
  for (int h = 0; h < 2; h++) {
    int d = t + h * 256;
    desc[(long)b * DKN + (long)d * KK + k] = v[h] * sc;
  }
  if (t == 0) atomicAdd(&gsq[b], tot * sc * sc);
}

// ---------------------------------------------------------------------------
// K4: whiten GEMM (memory-bound, streams W exactly once = 512 MB).
// grid (512 o-tiles, 2 j-slices); block = 8 out rows x 8 batches;
// thread float4-strided over its j-slice.
// ---------------------------------------------------------------------------
__global__ __launch_bounds__(256) void k4_whiten(
    const float* __restrict__ desc, const float* __restrict__ W,
    float* __restrict__ ydot) {
  int t = threadIdx.x;
  long o0 = (long)blockIdx.x * 8;
  int jbase = blockIdx.y * (DKN / 2);  // 16384
  float acc[8][8];  // [oo][bb]
#pragma unroll
  for (int oo = 0; oo < 8; oo++)
#pragma unroll
    for (int bb = 0; bb < 8; bb++) acc[oo][bb] = 0.f;

  const float* wbase = W + o0 * DKN;
  for (int jt = 0; jt < DKN / 2; jt += 1024) {  // 16 iterations
    int j = jbase + jt + t * 4;
    float4 d4[8];
#pragma unroll
    for (int bb = 0; bb < 8; bb++)
      d4[bb] = *(const float4*)(desc + (long)bb * DKN + j);
#pragma unroll
    for (int oo = 0; oo < 8; oo++) {
      float4 w4 = *(const float4*)(wbase + (long)oo * DKN + j);
#pragma unroll
      for (int bb = 0; bb < 8; bb++) {
        acc[oo][bb] += w4.x * d4[bb].x + w4.y * d4[bb].y +
                       w4.z * d4[bb].z + w4.w * d4[bb].w;
      }
    }
  }
  int lane = t & 63;
#pragma unroll
  for (int oo = 0; oo < 8; oo++)
#pragma unroll
    for (int bb = 0; bb < 8; bb++) {
      float v = acc[oo][bb];
      for (int off = 32; off > 0; off >>= 1) v += __shfl_down(v, off, 64);
      if (lane == 0) atomicAdd(&ydot[(long)bb * OUTN + o0 + oo], v);
    }
}

// ---------------------------------------------------------------------------
// K5: y = dot/gnorm + bias; final L2 normalize per row; write out.
// ---------------------------------------------------------------------------
__global__ __launch_bounds__(256) void k5_final(
    const float* __restrict__ ydot, const float* __restrict__ gsq,
    const float* __restrict__ bias, float* __restrict__ out) {
  __shared__ float sred[4];
  int b = blockIdx.x, t = threadIdx.x;
  float g = fmaxf(sqrtf(gsq[b]), 1e-12f);
  float inv_g = 1.0f / g;
  float v[16];
  float ss = 0.f;
#pragma unroll
  for (int i = 0; i < 16; i++) {
    int o = t + i * 256;
    float val = ydot[(long)b * OUTN + o] * inv_g + bias[o];
    v[i] = val;
    ss += val * val;
  }
  for (int off = 32; off > 0; off >>= 1) ss += __shfl_down(ss, off, 64);
  if ((t & 63) == 0) sred[t >> 6] = ss;
  __syncthreads();
  float tot = sred[0] + sred[1] + sred[2] + sred[3];
  float sc = 1.0f / fmaxf(sqrtf(tot), 1e-12f);
#pragma unroll
  for (int i = 0; i < 16; i++) {
    int o = t + i * 256;
    out[(long)b * OUTN + o] = v[i] * sc;
  }
}

extern "C" void kernel_launch(void* const* d_in, const int* in_sizes, int n_in,
                              void* d_out, int out_size, void* d_ws,
                              size_t ws_size, hipStream_t stream) {
  const float* x = (const float*)d_in[0];        // [8,512,40,40]
  const float* convw = (const float*)d_in[1];    // [64,512]
  const float* centers = (const float*)d_in[2];  // [512,64]
  const float* ww = (const float*)d_in[3];       // [4096,32768]
  const float* wb = (const float*)d_in[4];       // [4096]
  float* out = (float*)d_out;                    // [8,4096] f32

  // ws layout (floats):
  float* base = (float*)d_ws;
  float* ydot = base;                        // 8*4096      = 32768
  float* asum = base + 32768;                // 8*64        = 512
  float* gsq = base + 33280;                 // 8
  float* assignT = base + 33288;             // 8*1600*64   = 819200
  float* desc = assignT;                     // reuse (assignT dead after k2)
  float* vpT = base + 33288 + 819200;        // 25*8*512*64 = 6553600

  // zero the atomic accumulators (ydot, asum, gsq)
  hipMemsetAsync(base, 0, 33288 * sizeof(float), stream);

  hipLaunchKernelGGL(k1_scores, dim3(25, 8), dim3(256), 0, stream, x, convw,
                     assignT, asum);
  hipLaunchKernelGGL(k2_vlad, dim3(8, NSPLIT, 8), dim3(256), 0, stream, x,
                     assignT, vpT);
  hipLaunchKernelGGL(k3_norm, dim3(64, 8), dim3(256), 0, stream, vpT, asum,
                     centers, desc, gsq);
  hipLaunchKernelGGL(k4_whiten, dim3(512, 2), dim3(256), 0, stream, desc, ww,
                     ydot);
  hipLaunchKernelGGL(k5_final, dim3(8), dim3(256), 0, stream, ydot, gsq, wb,
                     out);
}